// Round 12
// baseline (199.475 us; speedup 1.0000x reference)
//
#include <hip/hip_runtime.h>
#include <math.h>

// ---------------------------------------------------------------------------
// HyperbolicInfoNCE on MI355X — Round 18: ONE fused kernel (convert -> grid
// barrier -> gemm -> grid barrier -> finalize).
//
// R17 post-mortem: barrier-free wave-private pipeline REGRESSED (59.7us) —
// barriers exonerated too. Every intra-gemm suspect is now individually
// refuted; gemm floor ~48us. The ignored number: dur_us - gemm_dur == 60-62us
// CONSTANT across all 11 rounds, immune to convert/finalize rewrites.
// Convert's real work is ~7us, finalize ~3us -> ~50us is inter-dispatch /
// graph-node overhead of the 3-kernel pipeline. Attack THAT.
//
// R18: single dispatch, normal <<<>>> launch (graph-capture-safe).
// grid 512 x 512thr = R15's gemm geometry verbatim (measured 48.5us).
// Co-residency GUARANTEED by launch_bounds arithmetic (guide §1):
//   __launch_bounds__(512,4): k = 4 waves/EU x 4 EU / 8 waves/block
//   = 2 blocks/CU -> grid 512 = 2x256 exact; capacity by LDS = 3/CU > 2
//   -> all 512 resident -> hand-rolled grid barrier cannot deadlock.
// Barrier = single-use counter: threadfence; atomicAdd; spin (agent-scope
// load + s_sleep); threadfence. Fences at PHASE BOUNDARIES only (R5's
// disaster was per-tile fences in the hot loop; here the one-time L2
// writeback is ~5MB and the next phase re-reads that data anyway).
// Counters zeroed via hipMemsetAsync (capturable).
// ---------------------------------------------------------------------------

#define BDIM   8192
#define K_IN   129
#define K_PAD  160      // 5 * 32
#define BK     32
#define NKT    5        // k-tiles of 32
#define CTILES 8        // 64-col tiles per block (256 rows x 512 cols)
#define GRID   512
#define NTHR   512

typedef __bf16  bf16x8 __attribute__((ext_vector_type(8)));
typedef float   f32x4  __attribute__((ext_vector_type(4)));
typedef unsigned short u16x4 __attribute__((ext_vector_type(4)));

// ws layout (bytes)
#define OFF_A    0u
#define OFF_B    (BDIM * K_PAD * 2u)                  // 2,621,440
#define OFF_RS   (2u * BDIM * K_PAD * 2u)             // 5,242,880
#define OFF_CP   (OFF_RS + BDIM * 4u)                 // 4 separated col replicas
#define OFF_DG   (OFF_CP + 4u * BDIM * 4u)
#define OFF_SYNC (OFF_DG + BDIM * 4u)                 // 2 x u32 barrier counters

// ---- hardware transcendentals ----
__device__ __forceinline__ float fast_sqrt(float x) {
#if __has_builtin(__builtin_amdgcn_sqrtf)
    return __builtin_amdgcn_sqrtf(x);
#else
    return sqrtf(x);
#endif
}
__device__ __forceinline__ float fast_log2(float x) {
#if __has_builtin(__builtin_amdgcn_logf)
    return __builtin_amdgcn_logf(x);
#else
    return __log2f(x);
#endif
}
__device__ __forceinline__ float fast_exp2(float x) {
#if __has_builtin(__builtin_amdgcn_exp2f)
    return __builtin_amdgcn_exp2f(x);
#else
    extern "C" __device__ float __ocml_native_exp2_f32(float);
    return __ocml_native_exp2_f32(x);
#endif
}

__device__ __forceinline__ unsigned short f2bf_rne(float f) {
    unsigned int u = __float_as_uint(f);
    u += 0x7FFFu + ((u >> 16) & 1u);   // round-to-nearest-even
    return (unsigned short)(u >> 16);
}

// Single-use grid barrier. Release: threadfence (agent) makes this block's
// plain stores + atomics visible; acquire: threadfence invalidates stale
// L1/L2 before the next phase reads.
__device__ __forceinline__ void grid_barrier(unsigned int* cnt) {
    __syncthreads();
    if (threadIdx.x == 0) {
        __threadfence();
        atomicAdd(cnt, 1u);
        while (__hip_atomic_load(cnt, __ATOMIC_RELAXED,
                                 __HIP_MEMORY_SCOPE_AGENT) < GRID)
            __builtin_amdgcn_s_sleep(2);
        __threadfence();
    }
    __syncthreads();
}

// ---------------------------------------------------------------------------
// Phase 2 helpers (R15 gemm verbatim): 8-wave block, 256 rows x 512 cols,
// shared 40KB double-buffered B tile via global_load_lds.
//   fragment layouts (guide-verified, m89/m91):
//     A/B operand: elem [m=lane&15][k=(lane>>4)*8 + j]
//     C/D:         elem [row=(lane>>4)*4 + reg][col=lane&15]
// ---------------------------------------------------------------------------

#define STAGE(bufidx, cb)                                                     \
    {                                                                         \
        const char* _gp = (const char*)(Bp + (size_t)(cb) * K_PAD)            \
                          + lane * 16;                                        \
        char* _lp = (char*)&Bs[bufidx][0];                                    \
        __builtin_amdgcn_global_load_lds(                                     \
            (const __attribute__((address_space(1))) void*)                   \
                (_gp + wave * 1024),                                          \
            (__attribute__((address_space(3))) void*)(_lp + wave * 1024),     \
            16, 0, 0);                                                        \
        __builtin_amdgcn_global_load_lds(                                     \
            (const __attribute__((address_space(1))) void*)                   \
                (_gp + (wave + 8) * 1024),                                    \
            (__attribute__((address_space(3))) void*)(_lp + (wave + 8) * 1024),\
            16, 0, 0);                                                        \
        if (wave < 4)                                                         \
            __builtin_amdgcn_global_load_lds(                                 \
                (const __attribute__((address_space(1))) void*)               \
                    (_gp + (wave + 16) * 1024),                               \
                (__attribute__((address_space(3))) void*)(_lp + (wave + 16) * 1024),\
                16, 0, 0);                                                    \
    }

#define COMPUTE(bufidx, cb)                                                   \
    {                                                                         \
        const int colBase = (cb);                                             \
        const unsigned short* _Bt = &Bs[bufidx][0];                           \
        f32x4 acc[2][4] = {};                                                 \
        _Pragma("unroll")                                                     \
        for (int kt = 0; kt < NKT; ++kt) {                                    \
            bf16x8 bfr[4];                                                    \
            _Pragma("unroll")                                                 \
            for (int j = 0; j < 4; ++j)                                       \
                bfr[j] = *(const bf16x8*)                                     \
                    &_Bt[(l16 + j * 16) * K_PAD + quad * 8 + kt * BK];        \
            _Pragma("unroll")                                                 \
            for (int i = 0; i < 2; ++i)                                       \
                _Pragma("unroll")                                             \
                for (int j = 0; j < 4; ++j)                                   \
                    acc[i][j] = __builtin_amdgcn_mfma_f32_16x16x32_bf16(      \
                        Ah[i][kt], bfr[j], acc[i][j], 0, 0, 0);               \
        }                                                                     \
        const bool diagTile = (colBase == (rowBase & ~63));                   \
        const int  dj       = (rowBase >> 4) & 2;                             \
        float colp[4] = {0.f, 0.f, 0.f, 0.f};                                 \
        _Pragma("unroll")                                                     \
        for (int i = 0; i < 2; ++i) {                                         \
            _Pragma("unroll")                                                 \
            for (int j = 0; j < 4; ++j) {                                     \
                _Pragma("unroll")                                             \
                for (int reg = 0; reg < 4; ++reg) {                           \
                    float inner = acc[i][j][reg];                             \
                    float x = fmaxf(-inner, 1.000001f);                       \
                    float s = fast_sqrt(__builtin_fmaf(x, x, -1.0f));         \
                    float l2u = fast_log2(x + s);                             \
                    float e = fast_exp2(-14.285714285714286f * l2u);          \
                    rowp[i][reg] += e;                                        \
                    colp[j]      += e;                                        \
                    if (diagTile && (j - i) == dj && (quad * 4 + reg) == l16){\
                        int R = rowBase + i * 16 + quad * 4 + reg;            \
                        diag[R] = -9.902102579427789f * l2u;                  \
                    }                                                         \
                }                                                             \
            }                                                                 \
        }                                                                     \
        _Pragma("unroll")                                                     \
        for (int j = 0; j < 4; ++j) {                                         \
            float v = colp[j];                                                \
            v += __shfl_xor(v, 16);                                           \
            v += __shfl_xor(v, 32);                                           \
            if (quad == 0)                                                    \
                atomicAdd(&colRep[colBase + j * 16 + l16], v);                \
        }                                                                     \
    }

// ---------------------------------------------------------------------------
__global__ __launch_bounds__(NTHR, 4) void fused_kernel(
    const float* __restrict__ z1, const float* __restrict__ z2,
    unsigned short* __restrict__ A, unsigned short* __restrict__ Bp,
    float* __restrict__ row_sum, float* __restrict__ col_part,
    float* __restrict__ diag, unsigned int* __restrict__ sync0,
    unsigned int* __restrict__ sync1, float* __restrict__ out)
{
    const int t   = threadIdx.x;
    const int bid = blockIdx.x;

    // ================= phase 1: convert + zero accumulators =================
    {
        int tidg = bid * NTHR + t;                 // 0..262143
        if (tidg < 5 * BDIM) row_sum[tidg] = 0.f;  // rs + 4 col replicas
        if (tidg == 0) out[0] = 0.f;
        for (int v = tidg; v < BDIM * (K_PAD / 4); v += GRID * NTHR) {
            int r  = v / (K_PAD / 4);
            int c4 = (v - r * (K_PAD / 4)) * 4;
            u16x4 a, b;
            #pragma unroll
            for (int i = 0; i < 4; ++i) {
                int c = c4 + i;
                float va = 0.f, vb = 0.f;
                if (c < K_IN) {
                    va = z1[r * K_IN + c];
                    vb = z2[r * K_IN + c];
                    if (c == 0) va = -va;          // Lorentz metric on coord 0
                }
                a[i] = f2bf_rne(va);
                b[i] = f2bf_rne(vb);
            }
            *(u16x4*)(A + r * K_PAD + c4)  = a;
            *(u16x4*)(Bp + r * K_PAD + c4) = b;
        }
    }

    grid_barrier(sync0);

    // ================= phase 2: strip-GEMM + fused epilogue =================
    {
        const int lane = t & 63;
        const int wave = t >> 6;                      // 0..7
        const int quad = lane >> 4;
        const int l16  = lane & 15;

        const int strip = bid & 31;                   // 0..31 (256-row strips)
        const int chunk = bid >> 5;                   // 0..15 (512-col chunks)
        const int rowBase  = strip * 256 + wave * 32;
        const int colChunk = chunk * 512;

        const unsigned short* Abase = A + (rowBase + l16) * K_PAD + quad * 8;
        float* colRep = col_part + (strip & 3) * BDIM;

        __shared__ __align__(16) unsigned short Bs[2][64 * K_PAD];  // 40,960B

        bf16x8 Ah[2][NKT];
        #pragma unroll
        for (int i = 0; i < 2; ++i)
            #pragma unroll
            for (int kt = 0; kt < NKT; ++kt)
                Ah[i][kt] = *(const bf16x8*)(Abase + i * 16 * K_PAD + kt * BK);

        float rowp[2][4] = {};

        STAGE(0, colChunk);
        __syncthreads();

        #pragma unroll 1
        for (int ct = 0; ct < CTILES; ++ct) {
            if (ct + 1 < CTILES)
                STAGE((ct + 1) & 1, colChunk + (ct + 1) * 64);
            COMPUTE(ct & 1, colChunk + ct * 64);
            __syncthreads();
        }

        #pragma unroll
        for (int i = 0; i < 2; ++i) {
            #pragma unroll
            for (int reg = 0; reg < 4; ++reg) {
                float v = rowp[i][reg];
                v += __shfl_xor(v, 1);
                v += __shfl_xor(v, 2);
                v += __shfl_xor(v, 4);
                v += __shfl_xor(v, 8);
                if (l16 == 0)
                    atomicAdd(&row_sum[rowBase + i * 16 + quad * 4 + reg], v);
            }
        }
    }

    grid_barrier(sync1);

    // ================= phase 3: finalize (block bid -> rows 16b..16b+15) ====
    if (t < 16) {
        const float LN2_HALF = 0.34657359027997264f;  // 0.5 * ln2
        int b = bid * 16 + t;
        float cs = col_part[b] + col_part[b + BDIM] +
                   col_part[b + 2 * BDIM] + col_part[b + 3 * BDIM];
        float a = LN2_HALF * (fast_log2(row_sum[b]) + fast_log2(cs)) - diag[b];
        a += __shfl_xor(a, 1);
        a += __shfl_xor(a, 2);
        a += __shfl_xor(a, 4);
        a += __shfl_xor(a, 8);
        if (t == 0)
            atomicAdd(out, a * (1.0f / (float)BDIM));
    }
}

// ---------------------------------------------------------------------------
extern "C" void kernel_launch(void* const* d_in, const int* in_sizes, int n_in,
                              void* d_out, int out_size, void* d_ws, size_t ws_size,
                              hipStream_t stream)
{
    const float* z1 = (const float*)d_in[0];
    const float* z2 = (const float*)d_in[1];
    float* out = (float*)d_out;

    char* ws = (char*)d_ws;
    unsigned short* A  = (unsigned short*)(ws + OFF_A);
    unsigned short* B  = (unsigned short*)(ws + OFF_B);
    float* row_sum     = (float*)(ws + OFF_RS);
    float* col_part    = (float*)(ws + OFF_CP);
    float* diag        = (float*)(ws + OFF_DG);
    unsigned int* sync = (unsigned int*)(ws + OFF_SYNC);

    // zero the two barrier counters (capturable async memset)
    hipMemsetAsync(sync, 0, 2 * sizeof(unsigned int), stream);

    fused_kernel<<<GRID, NTHR, 0, stream>>>(
        z1, z2, A, B, row_sum, col_part, diag, sync, sync + 1, out);
}

// Round 13
// 109.916 us; speedup vs baseline: 1.8148x; 1.8148x over previous
//
#include <hip/hip_runtime.h>
#include <math.h>

// ---------------------------------------------------------------------------
// HyperbolicInfoNCE on MI355X — Round 19: true 16 waves/CU via 20.5KB LDS.
//
// R18 post-mortem: fused single-kernel = 152us. Grid barrier cost = R5's
// lesson re-learned: per-block agent-scope fences (L2 wb/inv on multi-XCD)
// + 512-way contended counter RMW ~= 90us. Fences per block are poison.
// BUT R18 measured the decisive number: total - kernel = 47us with ONE
// dispatch -> the "60us residual" is ~47us fixed harness overhead, NOT
// per-dispatch gaps. Objective = minimize SUM of kernel durations; only a
// faster gemm moves the total. Revert to the 3-kernel structure.
//
// R19 = R14 with ONE variable: B-tile 64 -> 32 cols (CTILES=16), LDS
// 2 x 32 x 160 x 2B = 20,480B. R14's 4x40960 = exact-160KB was refused by
// the allocator (occupancy stuck 30%); 4x20.5K = 82KB has 78KB slack
// (capacity 7 by LDS). Grid 1024 = 64 strips x 16 chunks -> flat 4
// blocks/CU = 16 waves/CU, tail-free, no exact-fit fragility. acc shrinks
// to [2][2] (~80 combined regs << 128 cap). Occupancy is the one lever
// with measured positive slope (18.6->57.2, 22.8->55.4, 30.8->48.3us);
// this cleanly tests the 16-wave point. If dur stays ~48: gemm is at its
// structural floor -> roofline next round.
// ---------------------------------------------------------------------------

#define BDIM   8192
#define K_IN   129
#define K_PAD  160      // 5 * 32
#define BK     32
#define NKT    5        // k-tiles of 32
#define CTILES 16       // 32-col tiles per block (128 rows x 512 cols)

typedef __bf16  bf16x8 __attribute__((ext_vector_type(8)));
typedef float   f32x4  __attribute__((ext_vector_type(4)));
typedef unsigned short u16x4 __attribute__((ext_vector_type(4)));

// ws layout (bytes)
#define OFF_A    0u
#define OFF_B    (BDIM * K_PAD * 2u)                  // 2,621,440
#define OFF_RS   (2u * BDIM * K_PAD * 2u)             // 5,242,880
#define OFF_CP   (OFF_RS + BDIM * 4u)                 // 4 separated col replicas
#define OFF_DG   (OFF_CP + 4u * BDIM * 4u)

// ---- hardware transcendentals (v_sqrt_f32 / v_log_f32 / v_exp_f32) ----
__device__ __forceinline__ float fast_sqrt(float x) {
#if __has_builtin(__builtin_amdgcn_sqrtf)
    return __builtin_amdgcn_sqrtf(x);
#else
    return sqrtf(x);
#endif
}
__device__ __forceinline__ float fast_log2(float x) {
#if __has_builtin(__builtin_amdgcn_logf)
    return __builtin_amdgcn_logf(x);       // log base 2
#else
    return __log2f(x);
#endif
}
__device__ __forceinline__ float fast_exp2(float x) {
#if __has_builtin(__builtin_amdgcn_exp2f)
    return __builtin_amdgcn_exp2f(x);      // 2^x
#else
    extern "C" __device__ float __ocml_native_exp2_f32(float);
    return __ocml_native_exp2_f32(x);
#endif
}

__device__ __forceinline__ unsigned short f2bf_rne(float f) {
    unsigned int u = __float_as_uint(f);
    u += 0x7FFFu + ((u >> 16) & 1u);   // round-to-nearest-even
    return (unsigned short)(u >> 16);
}

// ---------------------------------------------------------------------------
// Kernel 1: fp32 -> bf16, float4-granular. K zero-padded 129->160, Lorentz
// metric folded into A (negate col 0). Also zeroes row_sum + 4 col replicas.
// ---------------------------------------------------------------------------
__global__ __launch_bounds__(256) void convert_kernel(
    const float* __restrict__ z1, const float* __restrict__ z2,
    unsigned short* __restrict__ A, unsigned short* __restrict__ B,
    float* __restrict__ rs_cp)
{
    int v = blockIdx.x * 256 + threadIdx.x;
    if (v < 5 * BDIM) rs_cp[v] = 0.f;          // rs (8192) + cp (4*8192)
    if (v >= BDIM * (K_PAD / 4)) return;
    int r  = v / (K_PAD / 4);
    int c4 = (v - r * (K_PAD / 4)) * 4;
    u16x4 a, b;
    #pragma unroll
    for (int i = 0; i < 4; ++i) {
        int c = c4 + i;
        float va = 0.f, vb = 0.f;
        if (c < K_IN) {
            va = z1[r * K_IN + c];
            vb = z2[r * K_IN + c];
            if (c == 0) va = -va;              // Lorentz metric on coord 0
        }
        a[i] = f2bf_rne(va);
        b[i] = f2bf_rne(vb);
    }
    *(u16x4*)(A + r * K_PAD + c4) = a;
    *(u16x4*)(B + r * K_PAD + c4) = b;
}

// ---------------------------------------------------------------------------
// Kernel 2: strip-GEMM with fused acosh/exp epilogue; B staged through a
// double-buffered LDS pipeline (global_load_lds), 32-col tiles.
//   grid = 1024: bid = chunk*64 + strip  (consecutive blocks share B-chunk)
//   block: rows [strip*128, +128) x cols [chunk*512, +512), 16 tiles of 32
//   wave w (0..3): rows [strip*128 + w*32, +32)
//   4 blocks/CU resident (LDS 20480B, 82KB/CU total; launch_bounds(256,4)).
//   fragment layouts (guide-verified, m89/m91):
//     A/B operand: elem [m=lane&15][k=(lane>>4)*8 + j]
//     C/D:         elem [row=(lane>>4)*4 + reg][col=lane&15]
// ---------------------------------------------------------------------------

// Stage one 32-col B-tile (10,240B contiguous global chunk) into Bs[bufidx]:
// 10 x 1KB issues split 3/3/2/2 across 4 waves. LDS dest wave-uniform +
// lane*16 (m104). Pure linear byte copy.
#define STAGE(bufidx, cb)                                                     \
    {                                                                         \
        const char* _gp = (const char*)(B + (size_t)(cb) * K_PAD)             \
                          + lane * 16;                                        \
        char* _lp = (char*)&Bs[bufidx][0];                                    \
        for (int _m = wave; _m < 10; _m += 4)                                 \
            __builtin_amdgcn_global_load_lds(                                 \
                (const __attribute__((address_space(1))) void*)               \
                    (_gp + _m * 1024),                                        \
                (__attribute__((address_space(3))) void*)(_lp + _m * 1024),   \
                16, 0, 0);                                                    \
    }

// MFMA + fused epilogue for one 32x32 wave-tile read from Bs[bufidx].
#define COMPUTE(bufidx, cb)                                                   \
    {                                                                         \
        const int colBase = (cb);                                             \
        const unsigned short* _Bt = &Bs[bufidx][0];                           \
        f32x4 acc[2][2] = {};                                                 \
        _Pragma("unroll")                                                     \
        for (int kt = 0; kt < NKT; ++kt) {                                    \
            bf16x8 bfr[2];                                                    \
            _Pragma("unroll")                                                 \
            for (int j = 0; j < 2; ++j)                                       \
                bfr[j] = *(const bf16x8*)                                     \
                    &_Bt[(l16 + j * 16) * K_PAD + quad * 8 + kt * BK];        \
            _Pragma("unroll")                                                 \
            for (int i = 0; i < 2; ++i)                                       \
                _Pragma("unroll")                                             \
                for (int j = 0; j < 2; ++j)                                   \
                    acc[i][j] = __builtin_amdgcn_mfma_f32_16x16x32_bf16(      \
                        Ah[i][kt], bfr[j], acc[i][j], 0, 0, 0);               \
        }                                                                     \
        const bool diagTile = (colBase == rowBase);                           \
        float colp[2] = {0.f, 0.f};                                           \
        _Pragma("unroll")                                                     \
        for (int i = 0; i < 2; ++i) {                                         \
            _Pragma("unroll")                                                 \
            for (int j = 0; j < 2; ++j) {                                     \
                _Pragma("unroll")                                             \
                for (int reg = 0; reg < 4; ++reg) {                           \
                    float inner = acc[i][j][reg];                             \
                    float x = fmaxf(-inner, 1.000001f);                       \
                    float s = fast_sqrt(__builtin_fmaf(x, x, -1.0f));         \
                    float l2u = fast_log2(x + s);                             \
                    float e = fast_exp2(-14.285714285714286f * l2u);          \
                    rowp[i][reg] += e;                                        \
                    colp[j]      += e;                                        \
                    if (diagTile && i == j && (quad * 4 + reg) == l16) {      \
                        int R = rowBase + i * 16 + quad * 4 + reg;            \
                        diag[R] = -9.902102579427789f * l2u;                  \
                    }                                                         \
                }                                                             \
            }                                                                 \
        }                                                                     \
        _Pragma("unroll")                                                     \
        for (int j = 0; j < 2; ++j) {                                         \
            float v = colp[j];                                                \
            v += __shfl_xor(v, 16);                                           \
            v += __shfl_xor(v, 32);                                           \
            if (quad == 0)                                                    \
                atomicAdd(&colRep[colBase + j * 16 + l16], v);                \
        }                                                                     \
    }

__global__ __launch_bounds__(256, 4) void gemm_epilogue_kernel(
    const unsigned short* __restrict__ A, const unsigned short* __restrict__ B,
    float* __restrict__ row_sum, float* __restrict__ col_part,
    float* __restrict__ diag)
{
    const int t    = threadIdx.x;
    const int lane = t & 63;
    const int wave = t >> 6;
    const int quad = lane >> 4;
    const int l16  = lane & 15;

    const int strip = blockIdx.x & 63;
    const int chunk = blockIdx.x >> 6;                // 0..15
    const int rowBase  = strip * 128 + wave * 32;     // wave's first row
    const int colChunk = chunk * 512;                 // block's first col

    const unsigned short* Abase = A + (rowBase + l16) * K_PAD + quad * 8;
    float* colRep = col_part + (strip & 3) * BDIM;    // contention / 4

    // B-tile double buffer: 2 x 32 x 160 shorts = 20,480B. 4 blocks/CU with
    // 78KB slack (no exact-fit fragility).
    __shared__ __align__(16) unsigned short Bs[2][32 * K_PAD];

    // ---- hoist the entire A operand for this wave: 2 row-frags x 5 k-tiles
    bf16x8 Ah[2][NKT];
    #pragma unroll
    for (int i = 0; i < 2; ++i)
        #pragma unroll
        for (int kt = 0; kt < NKT; ++kt)
            Ah[i][kt] = *(const bf16x8*)(Abase + i * 16 * K_PAD + kt * BK);

    float rowp[2][4] = {};   // persistent across all col-tiles

    // ---- 2-phase pipeline: stage next tile, compute current, one barrier
    STAGE(0, colChunk);                  // prologue: tile 0 -> Bs[0]
    __syncthreads();

    #pragma unroll 1
    for (int ct = 0; ct < CTILES; ++ct) {
        if (ct + 1 < CTILES)
            STAGE((ct + 1) & 1, colChunk + (ct + 1) * 32);
        COMPUTE(ct & 1, colChunk + ct * 32);
        __syncthreads();                 // drains stage loads (done under compute)
    }

    // row sums: accumulated over all 16 col-tiles; reduce across the 16
    // lanes of each quad (they hold the cols), one atomic per row
    #pragma unroll
    for (int i = 0; i < 2; ++i) {
        #pragma unroll
        for (int reg = 0; reg < 4; ++reg) {
            float v = rowp[i][reg];
            v += __shfl_xor(v, 1);
            v += __shfl_xor(v, 2);
            v += __shfl_xor(v, 4);
            v += __shfl_xor(v, 8);
            if (l16 == 0)
                atomicAdd(&row_sum[rowBase + i * 16 + quad * 4 + reg], v);
        }
    }
}

// ---------------------------------------------------------------------------
// Kernel 3: loss = mean_b( 0.5*(ln rs[b] + ln cs[b]) - diag[b] ),
// cs[b] = sum of 4 separated replicas.
// ---------------------------------------------------------------------------
__global__ __launch_bounds__(1024) void finalize_kernel(
    const float* __restrict__ rs, const float* __restrict__ cp,
    const float* __restrict__ dg, float* __restrict__ out)
{
    __shared__ float part[16];
    int t = threadIdx.x;
    float a = 0.f;
    const float LN2_HALF = 0.34657359027997264f;  // 0.5 * ln2
    for (int b = t; b < BDIM; b += 1024) {
        float cs = cp[b] + cp[b + BDIM] + cp[b + 2 * BDIM] + cp[b + 3 * BDIM];
        a += LN2_HALF * (fast_log2(rs[b]) + fast_log2(cs)) - dg[b];
    }
    #pragma unroll
    for (int m = 1; m < 64; m <<= 1) a += __shfl_xor(a, m);
    if ((t & 63) == 0) part[t >> 6] = a;
    __syncthreads();
    if (t < 16) {
        float v = part[t];
        #pragma unroll
        for (int m = 1; m < 16; m <<= 1) v += __shfl_xor(v, m);
        if (t == 0) out[0] = v * (1.0f / (float)BDIM);
    }
}

// ---------------------------------------------------------------------------
extern "C" void kernel_launch(void* const* d_in, const int* in_sizes, int n_in,
                              void* d_out, int out_size, void* d_ws, size_t ws_size,
                              hipStream_t stream)
{
    const float* z1 = (const float*)d_in[0];
    const float* z2 = (const float*)d_in[1];
    float* out = (float*)d_out;

    char* ws = (char*)d_ws;
    unsigned short* A  = (unsigned short*)(ws + OFF_A);
    unsigned short* B  = (unsigned short*)(ws + OFF_B);
    float* row_sum     = (float*)(ws + OFF_RS);
    float* col_part    = (float*)(ws + OFF_CP);
    float* diag        = (float*)(ws + OFF_DG);

    convert_kernel<<<(BDIM * (K_PAD / 4) + 255) / 256, 256, 0, stream>>>(
        z1, z2, A, B, row_sum /* rs + 4 separated col replicas contiguous */);

    gemm_epilogue_kernel<<<1024, 256, 0, stream>>>(
        A, B, row_sum, col_part, diag);

    finalize_kernel<<<1, 1024, 0, stream>>>(row_sum, col_part, diag, out);
}